// Round 4
// baseline (21183.473 us; speedup 1.0000x reference)
//
#include <hip/hip_runtime.h>

#define HH 200   // hidden
#define GG 800   // 4*H
#define DD 24    // d_model
#define BB 64    // batch
#define TT 2048  // timesteps
#define CH 16    // chunk length for ux precompute
#define NQ 8     // h-dim slices (blocks per batch-pair)
#define NRG 32   // batch-pair groups
#define KD 25    // dims per block = HH/NQ
#define NT 256   // threads per block
#define NCHUNK (TT / CH)

typedef float f32x2 __attribute__((ext_vector_type(2)));
typedef float f32x4 __attribute__((ext_vector_type(4)));

__device__ __forceinline__ f32x2 lo4(f32x4 v) { return __builtin_shufflevector(v, v, 0, 1); }
__device__ __forceinline__ f32x2 hi4(f32x4 v) { return __builtin_shufflevector(v, v, 2, 3); }

__device__ __forceinline__ float fsig(float x) {
    float e = __expf(-x);
    return 1.f / (1.f + e);
}
__device__ __forceinline__ float ftanh(float x) {
    float e = __expf(2.f * x);
    return 1.f - 2.f / (e + 1.f);
}

// ws layout: bytes [0,4096): counters, u32 at rg*32 words (128 B apart)
//            bytes [4096, 4096+102400): float sdata[2][NRG][NQ][2][KD]
#define WS_NEED (4096 + 2 * NRG * NQ * 2 * KD * 4)

__device__ __forceinline__ int sl(int par, int rg, int q, int b, int k) {
    return (((par * NRG + rg) * NQ + q) * 2 + b) * KD + k;
}

__global__ void init_ws(unsigned int* ws) {
    int i = threadIdx.x + blockIdx.x * blockDim.x;
    if (i < 1024) ws[i] = 0u;   // counters region
}

__global__ __launch_bounds__(NT, 1)
void lstm_split(const float* __restrict__ emb,     // [B,T,D]
                const float* __restrict__ h_past,  // [B,T,H]
                const float* __restrict__ U_w,     // [4H,H]
                const float* __restrict__ U_b,     // [4H]
                const float* __restrict__ W_w,     // [4H,H]
                const float* __restrict__ V_w,     // [H,D]
                const float* __restrict__ V_b,     // [H]
                const float* __restrict__ h0,      // [1,H]
                const float* __restrict__ c0,      // [1,H]
                float* __restrict__ ws,            // exchange buffers
                float* __restrict__ out)           // [B,T,H]
{
    __shared__ f32x4 Wt4[50 * 100];                // 80,000 B  Wt4[j4*100+r]
    __shared__ float hp_sh[2][CH][2][HH];          // 51,200 B
    __shared__ float emb_sh[2][CH][2][DD];         //  6,144 B
    __shared__ float h_sh[2][HH];                  //  1,600 B
    __shared__ float Vw_sh[KD][DD];                //  2,400 B
    __shared__ float Vb_sh[KD];
    __shared__ float g_sh[100][2];                 //    800 B

    const int tid = threadIdx.x;
    const int bid = blockIdx.x;
    const int rg  = bid & (NRG - 1);   // peers stride 32 apart -> same XCD (bid%8 equal)
    const int q   = bid >> 5;          // 0..7
    const int b0  = 2 * rg;            // global batches b0, b0+1

    unsigned int* cnt = (unsigned int*)ws + (size_t)rg * 32;
    float* sdata = ws + 1024;          // slice data

    // ---- gate-thread constants ----
    const bool is_gate = (tid < 200);
    const int r = tid >> 1;            // local gate row 0..99
    const int b = tid & 1;
    int gr = 0;
    if (is_gate) gr = (r / KD) * HH + q * KD + (r % KD);   // global gate row
    const float ub = is_gate ? U_b[gr] : 0.f;
    const f32x4* Urow = (const f32x4*)(U_w + (size_t)gr * HH);

    // ---- updater constants ----
    const bool is_upd = (tid < 2 * KD);
    const int bu = tid / KD;           // batch (0/1) for updater
    const int ku = tid % KD;           // local dim
    float c_reg = is_upd ? c0[q * KD + ku] : 0.f;

    // ---- one-time staging ----
    for (int idx = tid; idx < 100 * 50; idx += NT) {
        int rr = idx / 50, j4 = idx % 50;
        int grr = (rr / KD) * HH + q * KD + (rr % KD);
        Wt4[j4 * 100 + rr] = *(const f32x4*)(W_w + (size_t)grr * HH + 4 * j4);
    }
    for (int idx = tid; idx < KD * DD; idx += NT)
        Vw_sh[idx / DD][idx % DD] = V_w[(q * KD + idx / DD) * DD + idx % DD];
    if (tid < KD) Vb_sh[tid] = V_b[q * KD + tid];
    // BUGFIX (round 3): was `if (tid < 2*HH)` with NT=256 < 400 threads, leaving
    // h_sh[1][56..199] uninitialized -> garbage h0 for odd batches (absmax 0.358).
    for (int i = tid; i < 2 * HH; i += NT) h_sh[i / HH][i % HH] = h0[i % HH];

    // stage chunk 0 (hp + emb) into buf 0
    {
        const int t0 = 0, buf = 0;
        for (int idx = tid; idx < CH * 2 * HH; idx += NT) {
            int s = idx / (2 * HH), rm = idx % (2 * HH), bb = rm / HH, j = rm % HH;
            hp_sh[buf][s][bb][j] = h_past[((size_t)(b0 + bb) * TT + (t0 + s)) * HH + j];
        }
        for (int idx = tid; idx < CH * 2 * DD; idx += NT) {
            int s = idx / (2 * DD), rm = idx % (2 * DD), bb = rm / DD, d = rm % DD;
            emb_sh[buf][s][bb][d] = emb[((size_t)(b0 + bb) * TT + (t0 + s)) * DD + d];
        }
    }
    __syncthreads();

    // ux accumulators: uxn = being built (next chunk), uxc = current chunk (shifted down each step)
    f32x2 uxc[CH], uxn[CH];
    #pragma unroll
    for (int i = 0; i < CH; ++i) { uxc[i] = (f32x2){0.f, 0.f}; uxn[i] = (f32x2){0.f, 0.f}; }

    // prologue: full ux for chunk 0 into uxn (reads hp buf 0)
    if (is_gate) {
        for (int ps = 0; ps < CH; ++ps) {
            for (int j4 = ps; j4 < 50; j4 += CH) {
                f32x4 u = Urow[j4];
                #pragma unroll
                for (int s = 0; s < CH; ++s) {
                    f32x4 hp = *(const f32x4*)&hp_sh[0][s][b][4 * j4];
                    uxn[s] += lo4(u) * lo4(hp);
                    uxn[s] += hi4(u) * hi4(hp);
                }
            }
        }
    }

    for (int t = 0; t < TT; ++t) {
        const int s_in = t & (CH - 1);
        const int c    = t >> 4;            // chunk index
        const int cbuf = c & 1;             // emb buffer for current chunk
        const int nbuf = cbuf ^ 1;          // hp/emb buffer for next chunk
        const bool has_next = (t + CH < TT);
        const int par1 = (t + 1) & 1;

        if (s_in == 0) {
            // promote next-chunk ux accumulators to current; clear next
            #pragma unroll
            for (int i = 0; i < CH; ++i) { uxc[i] = uxn[i]; uxn[i] = (f32x2){0.f, 0.f}; }
            // stage chunk c+1 into nbuf
            if (has_next) {
                const int t0n = (c + 1) * CH;
                for (int idx = tid; idx < CH * 2 * HH; idx += NT) {
                    int s = idx / (2 * HH), rm = idx % (2 * HH), bb = rm / HH, j = rm % HH;
                    hp_sh[nbuf][s][bb][j] = h_past[((size_t)(b0 + bb) * TT + (t0n + s)) * HH + j];
                }
                for (int idx = tid; idx < CH * 2 * DD; idx += NT) {
                    int s = idx / (2 * DD), rm = idx % (2 * DD), bb = rm / DD, d = rm % DD;
                    emb_sh[nbuf][s][bb][d] = emb[((size_t)(b0 + bb) * TT + (t0n + s)) * DD + d];
                }
            }
            __syncthreads();
        }

        // ---- gate dots: gv = W[row]·h + ux + ub ----
        if (is_gate) {
            f32x2 a = (f32x2){0.f, 0.f};
            const f32x4* hrow = (const f32x4*)&h_sh[b][0];
            #pragma unroll 10
            for (int j4 = 0; j4 < 50; ++j4) {
                f32x4 w = Wt4[j4 * 100 + r];
                f32x4 h = hrow[j4];
                a += lo4(w) * lo4(h);
                a += hi4(w) * hi4(h);
            }
            float gv = a.x + a.y + uxc[0].x + uxc[0].y + ub;
            // r/KD: 0=i,1=f,2=g(cell, tanh),3=o ; tanh(x) = 2*sig(2x)-1
            bool isg = (r >= 2 * KD) && (r < 3 * KD);
            float y = fsig(isg ? 2.f * gv : gv);
            g_sh[r][b] = isg ? 2.f * y - 1.f : y;
            // shift current-chunk ux accumulators down (static indexing)
            #pragma unroll
            for (int i = 0; i < CH - 1; ++i) uxc[i] = uxc[i + 1];
        }
        __syncthreads();   // B1: gates ready

        // ---- h/c update for own dims + publish ----
        if (is_upd) {
            float ig = g_sh[ku][bu];
            float fg = g_sh[KD + ku][bu];
            float zg = g_sh[2 * KD + ku][bu];
            float og = g_sh[3 * KD + ku][bu];
            c_reg = fmaf(fg, c_reg, ig * zg);
            float a = Vb_sh[ku];
            #pragma unroll
            for (int d = 0; d < DD; ++d)
                a = fmaf(emb_sh[cbuf][s_in][bu][d], Vw_sh[ku][d], a);
            float h = fmaf(og, ftanh(c_reg), ftanh(a));
            __hip_atomic_store(&sdata[sl(par1, rg, q, bu, ku)], h,
                               __ATOMIC_RELEASE, __HIP_MEMORY_SCOPE_AGENT);
            out[((size_t)(b0 + bu) * TT + t) * HH + q * KD + ku] = h;
        }
        __syncthreads();   // B2: all publishes issued & retired
                           // (tid0's release-RMW below is in wave 0, which also
                           //  issued the 50 publishes -> its vmcnt(0) drains them)

        if (tid == 0)
            __hip_atomic_fetch_add(cnt, 1u, __ATOMIC_RELEASE, __HIP_MEMORY_SCOPE_AGENT);

        // ---- hide exchange latency: ux slice for next chunk ----
        if (has_next && is_gate) {
            for (int j4 = s_in; j4 < 50; j4 += CH) {
                f32x4 u = Urow[j4];
                #pragma unroll
                for (int s = 0; s < CH; ++s) {
                    f32x4 hp = *(const f32x4*)&hp_sh[nbuf][s][b][4 * j4];
                    uxn[s] += lo4(u) * lo4(hp);
                    uxn[s] += hi4(u) * hi4(hp);
                }
            }
        }

        if (tid == 0) {
            const unsigned tgt = 8u * (unsigned)(t + 1);
            while (__hip_atomic_load(cnt, __ATOMIC_ACQUIRE, __HIP_MEMORY_SCOPE_AGENT) < tgt)
                __builtin_amdgcn_s_sleep(2);
        }
        __syncthreads();   // B3: all peers' slices available

        // ---- assemble h_{t+1} from the 8 slices ----
        for (int idx = tid; idx < NQ * 2 * KD; idx += NT) {
            int qq = idx / (2 * KD), rm = idx % (2 * KD), bb = rm / KD, k = rm % KD;
            float v = __hip_atomic_load(&sdata[sl(par1, rg, qq, bb, k)],
                                        __ATOMIC_RELAXED, __HIP_MEMORY_SCOPE_AGENT);
            h_sh[bb][qq * KD + k] = v;
        }
        __syncthreads();   // B4: h_sh ready for next step
    }
}

// -------- fallback (round-1 style, used only if ws_size is tiny) --------
#define FNT 832
__global__ __launch_bounds__(FNT)
void lstm_fallback(const float* __restrict__ emb, const float* __restrict__ h_past,
                   const float* __restrict__ U_w, const float* __restrict__ U_b,
                   const float* __restrict__ W_w, const float* __restrict__ V_w,
                   const float* __restrict__ V_b, const float* __restrict__ h0,
                   const float* __restrict__ c0, float* __restrict__ out)
{
    __shared__ float ux_sh[CH][GG];
    __shared__ float hp_sh[CH][HH];
    __shared__ float emb_sh[CH][DD];
    __shared__ float h_sh[HH];
    __shared__ float g_sh[GG];
    __shared__ float Vw_sh[HH][DD + 1];
    __shared__ float Vb_sh[HH];

    const int tid = threadIdx.x;
    const int bb = blockIdx.x;
    for (int i = tid; i < HH * DD; i += FNT) Vw_sh[i / DD][i % DD] = V_w[i];
    if (tid < HH) { Vb_sh[tid] = V_b[tid]; h_sh[tid] = h0[tid]; }
    float c = (tid < HH) ? c0[tid] : 0.f;
    const float ub = (tid < GG) ? U_b[tid] : 0.f;
    const float* hpb  = h_past + (size_t)bb * TT * HH;
    const float* embb = emb + (size_t)bb * TT * DD;
    float* outb = out + (size_t)bb * TT * HH;
    __syncthreads();
    for (int t0 = 0; t0 < TT; t0 += CH) {
        for (int i = tid; i < CH * HH; i += FNT) (&hp_sh[0][0])[i] = hpb[(size_t)t0 * HH + i];
        for (int i = tid; i < CH * DD; i += FNT) (&emb_sh[0][0])[i] = embb[(size_t)t0 * DD + i];
        __syncthreads();
        if (tid < GG) {
            float2 acc[CH];
            #pragma unroll
            for (int s = 0; s < CH; ++s) acc[s] = make_float2(0.f, 0.f);
            for (int j = 0; j < HH; j += 4) {
                float4 u4 = *(const float4*)(U_w + (size_t)tid * HH + j);
                #pragma unroll
                for (int s = 0; s < CH; ++s) {
                    float4 hp4 = *(const float4*)(&hp_sh[s][j]);
                    acc[s].x = fmaf(u4.x, hp4.x, acc[s].x);
                    acc[s].y = fmaf(u4.y, hp4.y, acc[s].y);
                    acc[s].x = fmaf(u4.z, hp4.z, acc[s].x);
                    acc[s].y = fmaf(u4.w, hp4.w, acc[s].y);
                }
            }
            #pragma unroll
            for (int s = 0; s < CH; ++s) ux_sh[s][tid] = acc[s].x + acc[s].y + ub;
        }
        __syncthreads();
        for (int s = 0; s < CH; ++s) {
            float ve = 0.f;
            if (tid < HH) {
                float a = Vb_sh[tid];
                #pragma unroll
                for (int d = 0; d < DD; ++d) a = fmaf(emb_sh[s][d], Vw_sh[tid][d], a);
                ve = ftanh(a);
            }
            if (tid < GG) {
                float2 g2 = make_float2(0.f, 0.f);
                for (int j = 0; j < HH; j += 4) {
                    float4 w4 = *(const float4*)(W_w + (size_t)tid * HH + j);
                    float4 h4 = *(const float4*)(&h_sh[j]);
                    g2.x = fmaf(w4.x, h4.x, g2.x);
                    g2.y = fmaf(w4.y, h4.y, g2.y);
                    g2.x = fmaf(w4.z, h4.z, g2.x);
                    g2.y = fmaf(w4.w, h4.w, g2.y);
                }
                float gv = g2.x + g2.y + ux_sh[s][tid];
                bool isg = (tid >= 2 * HH) && (tid < 3 * HH);
                g_sh[tid] = isg ? ftanh(gv) : fsig(gv);
            }
            __syncthreads();
            if (tid < HH) {
                float ig = g_sh[tid], fg = g_sh[HH + tid];
                float zg = g_sh[2 * HH + tid], og = g_sh[3 * HH + tid];
                c = fmaf(fg, c, ig * zg);
                float h = fmaf(og, ftanh(c), ve);
                h_sh[tid] = h;
                outb[(size_t)(t0 + s) * HH + tid] = h;
            }
            __syncthreads();
        }
    }
}

extern "C" void kernel_launch(void* const* d_in, const int* in_sizes, int n_in,
                              void* d_out, int out_size, void* d_ws, size_t ws_size,
                              hipStream_t stream) {
    const float* emb    = (const float*)d_in[0];
    const float* h_past = (const float*)d_in[1];
    const float* U_w    = (const float*)d_in[2];
    const float* U_b    = (const float*)d_in[3];
    const float* W_w    = (const float*)d_in[4];
    const float* V_w    = (const float*)d_in[5];
    const float* V_b    = (const float*)d_in[6];
    const float* h0     = (const float*)d_in[7];
    const float* c0     = (const float*)d_in[8];
    float* out = (float*)d_out;

    if (ws_size >= (size_t)WS_NEED) {
        init_ws<<<4, 256, 0, stream>>>((unsigned int*)d_ws);
        lstm_split<<<NRG * NQ, NT, 0, stream>>>(emb, h_past, U_w, U_b, W_w,
                                                V_w, V_b, h0, c0, (float*)d_ws, out);
    } else {
        lstm_fallback<<<BB, FNT, 0, stream>>>(emb, h_past, U_w, U_b, W_w,
                                              V_w, V_b, h0, c0, out);
    }
}